// Round 16
// baseline (225.581 us; speedup 1.0000x reference)
//
#include <hip/hip_runtime.h>
#include <math.h>

#ifndef M_PI
#define M_PI 3.14159265358979323846
#endif

#define T_ROWS 1024
#define EDIM   2048
#define IN_DIM 1024
#define OUT_DIM 1024
#define NMODES 16
#define NLAYERS 4

typedef __attribute__((ext_vector_type(8))) short bf16x8;
typedef __attribute__((ext_vector_type(4))) float f32x4;

__device__ __forceinline__ unsigned short f2bf(float f) {
  union { float f; unsigned u; } v; v.f = f;
  unsigned r = v.u + 0x7FFFu + ((v.u >> 16) & 1u);  // RNE
  return (unsigned short)(r >> 16);
}
__device__ __forceinline__ float bf2f(unsigned short h) {
  union { unsigned u; float f; } v; v.u = ((unsigned)h) << 16;
  return v.f;
}
__device__ __forceinline__ void f2bf_split(float v, unsigned short& h, unsigned short& l) {
  h = f2bf(v);
  l = f2bf(v - bf2f(h));
}

// B[K][N] fp32 -> BT[N][K] bf16, one 32x32 tile (device helper for setup_all)
__device__ __forceinline__ void transpose_tile(const float* __restrict__ B,
                                               unsigned short* __restrict__ BT,
                                               int K, int N, int k0, int n0, int tid,
                                               float (*tile)[33])
{
  {
    int r = tid >> 3, c4 = (tid & 7) * 4;
    float4 v = *(const float4*)&B[(size_t)(k0 + r) * N + n0 + c4];
    tile[r][c4 + 0] = v.x; tile[r][c4 + 1] = v.y;
    tile[r][c4 + 2] = v.z; tile[r][c4 + 3] = v.w;
  }
  __syncthreads();
  {
    int n = tid >> 3, kq = (tid & 7) * 4;
    ushort4 o;
    o.x = f2bf(tile[kq + 0][n]); o.y = f2bf(tile[kq + 1][n]);
    o.z = f2bf(tile[kq + 2][n]); o.w = f2bf(tile[kq + 3][n]);
    *(ushort4*)&BT[(size_t)(n0 + n) * K + k0 + kq] = o;
  }
}

// Fused setup.
// 0..7: ctab/stab | 8..263: basF frag table (slot31 = 1.0 bias) | 264: folded
// weights | 265..2312: WenT | 2313..4360: WdeT | 4361..4872: x -> x_bf cvt
__global__ __launch_bounds__(256)
void setup_all(float* __restrict__ ctab, float* __restrict__ stab,
               unsigned short* __restrict__ basFh, unsigned short* __restrict__ basFl,
               const float* __restrict__ fc0w, const float* __restrict__ fc0b,
               const float* __restrict__ wr, const float* __restrict__ wi,
               const float* __restrict__ pww, const float* __restrict__ pwb,
               float* __restrict__ Wmr, float* __restrict__ Wmi,
               float* __restrict__ b0r, float* __restrict__ pw1,
               float* __restrict__ pb1,
               const float* __restrict__ W_en, unsigned short* __restrict__ WenT,
               const float* __restrict__ W_de, unsigned short* __restrict__ WdeT,
               const float* __restrict__ x, unsigned short* __restrict__ x_bf)
{
  __shared__ float tile[32][33];
  const int b = blockIdx.x, tid = threadIdx.x;
  if (b < 8) {
    int i = b * 256 + tid;
    double ang = (2.0 * M_PI / (double)EDIM) * (double)i;
    ctab[i] = (float)cos(ang);
    stab[i] = (float)sin(ang);
  } else if (b < 264) {
    int idx = (b - 8) * 256 + tid;            // [0, 65536)
    int mt = idx >> 9;
    int l  = (idx >> 3) & 63;
    int i  = idx & 7;
    int xx = mt * 16 + (l & 15);
    int j  = (l >> 4) * 8 + i;
    float v;
    if (j < 31) {
      int m = (j < NMODES) ? j : (j - 15);
      int ia = (m * xx) & (EDIM - 1);
      double ang = (2.0 * M_PI / (double)EDIM) * (double)ia;
      v = (j < NMODES) ? (float)cos(ang) : (float)sin(ang);
    } else {
      v = 1.0f;                               // bias slot
    }
    unsigned short h, lo; f2bf_split(v, h, lo);
    basFh[idx] = h; basFl[idx] = lo;
  } else if (b == 264) {
    if (tid >= NLAYERS * 32) return;
    int l = tid >> 5, d = tid & 31;
    for (int m = 0; m < NMODES; ++m) {
      float sr = 0.f, si = 0.f;
      for (int c = 0; c < 32; ++c) {
        float w0 = fc0w[l * 32 + c];
        size_t base = ((size_t)(l * 32 + c) * 32 + d) * NMODES + m;
        sr += w0 * wr[base];
        si += w0 * wi[base];
      }
      Wmr[(l * NMODES + m) * 32 + d] = sr;
      Wmi[(l * NMODES + m) * 32 + d] = si;
    }
    float sb = 0.f, sp = 0.f, sq = 0.f;
    for (int c = 0; c < 32; ++c) {
      float b0 = fc0b[l * 32 + c];
      float w0 = fc0w[l * 32 + c];
      sb += b0 * wr[((size_t)(l * 32 + c) * 32 + d) * NMODES + 0];
      float pw = pww[(size_t)(l * 32 + c) * 32 + d];
      sp += w0 * pw;
      sq += b0 * pw;
    }
    b0r[l * 32 + d] = (float)EDIM * sb;
    pw1[l * 32 + d] = sp;
    pb1[l * 32 + d] = sq + pwb[l * 32 + d];
  } else if (b < 2313) {
    int tb = b - 265;                         // W_en: K=IN_DIM, N=EDIM
    int n0 = (tb & 63) * 32, k0 = (tb >> 6) * 32;
    transpose_tile(W_en, WenT, IN_DIM, EDIM, k0, n0, tid, tile);
  } else if (b < 4361) {
    int tb = b - 2313;                        // W_de: K=EDIM, N=OUT_DIM
    int n0 = (tb & 31) * 32, k0 = (tb >> 5) * 32;
    transpose_tile(W_de, WdeT, EDIM, OUT_DIM, k0, n0, tid, tile);
  } else {
    size_t i0 = ((size_t)(b - 4361) * 256 + tid) * 8;   // x cvt, 1M elements
    float4 a0 = *(const float4*)&x[i0];
    float4 a1 = *(const float4*)&x[i0 + 4];
    ushort4 o0, o1;
    o0.x = f2bf(a0.x); o0.y = f2bf(a0.y); o0.z = f2bf(a0.z); o0.w = f2bf(a0.w);
    o1.x = f2bf(a1.x); o1.y = f2bf(a1.y); o1.z = f2bf(a1.z); o1.w = f2bf(a1.w);
    *(ushort4*)&x_bf[i0]     = o0;
    *(ushort4*)&x_bf[i0 + 4] = o1;
  }
}

// C[M][N] = A[M][K](bf16) @ BT[N][K](bf16)^T + bias. 64x64 tile, BK=64.
// Double-buffered LDS + register prefetch (r14 structure, best measured).
#define BKK 64
__global__ __launch_bounds__(256)
void gemm_mfma(const unsigned short* __restrict__ A, const unsigned short* __restrict__ BT,
               const float* __restrict__ bias, float* __restrict__ C,
               int M, int N, int K)
{
  __shared__ __align__(16) unsigned short Asb[2][64 * BKK];
  __shared__ __align__(16) unsigned short Bsb[2][64 * BKK];
  const int tid = threadIdx.x;
  const int bm = blockIdx.y * 64, bn = blockIdx.x * 64;
  const int lane = tid & 63, wave = tid >> 6;
  const int wr = wave >> 1, wc = wave & 1;

  const int srow = tid >> 2;          // 0..63
  const int skq  = tid & 3;           // 16-k chunk

  f32x4 acc[2][2] = {};

  const unsigned short* aRow = A + (size_t)(bm + srow) * K + skq * 16;
  const unsigned short* bRow = BT + (size_t)(bn + srow) * K + skq * 16;

  int slot0 = (skq * 2 + 0) ^ ((srow >> 1) & 7);
  int slot1 = (skq * 2 + 1) ^ ((srow >> 1) & 7);

  bf16x8 pa0, pa1, pb0, pb1v;
  pa0 = *(const bf16x8*)(aRow + 0);
  pa1 = *(const bf16x8*)(aRow + 8);
  pb0 = *(const bf16x8*)(bRow + 0);
  pb1v = *(const bf16x8*)(bRow + 8);
  *(bf16x8*)&Asb[0][srow * BKK + slot0 * 8] = pa0;
  *(bf16x8*)&Asb[0][srow * BKK + slot1 * 8] = pa1;
  *(bf16x8*)&Bsb[0][srow * BKK + slot0 * 8] = pb0;
  *(bf16x8*)&Bsb[0][srow * BKK + slot1 * 8] = pb1v;

  int cur = 0;
  for (int k0 = 0; k0 < K; k0 += BKK) {
    __syncthreads();                         // buf[cur] ready
    const bool more = (k0 + BKK) < K;
    if (more) {
      pa0 = *(const bf16x8*)(aRow + k0 + BKK);
      pa1 = *(const bf16x8*)(aRow + k0 + BKK + 8);
      pb0 = *(const bf16x8*)(bRow + k0 + BKK);
      pb1v = *(const bf16x8*)(bRow + k0 + BKK + 8);
    }
    #pragma unroll
    for (int s = 0; s < 2; ++s) {
      int kb = s * 4 + (lane >> 4);
      bf16x8 a[2], b[2];
      #pragma unroll
      for (int i = 0; i < 2; ++i) {
        int ar = wr * 32 + i * 16 + (lane & 15);
        a[i] = *(const bf16x8*)&Asb[cur][ar * BKK + (kb ^ ((ar >> 1) & 7)) * 8];
        int br = wc * 32 + i * 16 + (lane & 15);
        b[i] = *(const bf16x8*)&Bsb[cur][br * BKK + (kb ^ ((br >> 1) & 7)) * 8];
      }
      #pragma unroll
      for (int i = 0; i < 2; ++i)
        #pragma unroll
        for (int j = 0; j < 2; ++j)
          acc[i][j] = __builtin_amdgcn_mfma_f32_16x16x32_bf16(a[i], b[j], acc[i][j], 0, 0, 0);
    }
    if (more) {
      const int nxt = cur ^ 1;
      *(bf16x8*)&Asb[nxt][srow * BKK + slot0 * 8] = pa0;
      *(bf16x8*)&Asb[nxt][srow * BKK + slot1 * 8] = pa1;
      *(bf16x8*)&Bsb[nxt][srow * BKK + slot0 * 8] = pb0;
      *(bf16x8*)&Bsb[nxt][srow * BKK + slot1 * 8] = pb1v;
    }
    cur ^= 1;
  }

  #pragma unroll
  for (int j = 0; j < 2; ++j) {
    int col = bn + wc * 32 + j * 16 + (lane & 15);
    float bz = bias[col];
    #pragma unroll
    for (int i = 0; i < 2; ++i)
      #pragma unroll
      for (int r = 0; r < 4; ++r) {
        int row = bm + wr * 32 + i * 16 + (lane >> 4) * 4 + r;
        C[(size_t)row * N + col] = acc[i][j][r] + bz;
      }
  }
}

// 16-mode DFT per row (twiddle recurrence, x<->x+1024 parity fold) + mode mix
// -> bf16 hi/lo fragments; slot31 = pb1. LDS two-phase reduce (r12 structure).
__global__ __launch_bounds__(256)
void dft_coef(const float* __restrict__ u,
              const float* __restrict__ ctab, const float* __restrict__ stab,
              const float* __restrict__ Wmr, const float* __restrict__ Wmi,
              const float* __restrict__ b0r, const float* __restrict__ pb1,
              unsigned short* __restrict__ coefFh, unsigned short* __restrict__ coefFl)
{
  const int t = blockIdx.x, tid = threadIdx.x;
  __shared__ float dred[32][264];
  __shared__ float Ush[32];

  float pr[NMODES], pi[NMODES];
  #pragma unroll
  for (int m = 0; m < NMODES; ++m) { pr[m] = 0.f; pi[m] = 0.f; }
  #pragma unroll
  for (int it = 0; it < 4; ++it) {
    const int x = tid + it * 256;
    const float v0 = u[(size_t)t * EDIM + x];
    const float v1 = u[(size_t)t * EDIM + x + 1024];
    const float ve = v0 + v1, vo = v0 - v1;
    const float cx = ctab[x], sx = stab[x];
    float c = 1.f, s = 0.f;
    #pragma unroll
    for (int m = 0; m < NMODES; ++m) {
      const float vsel = (m & 1) ? vo : ve;
      pr[m] += vsel * c;
      pi[m] -= vsel * s;
      float cn = c * cx - s * sx;
      s = s * cx + c * sx;
      c = cn;
    }
  }
  #pragma unroll
  for (int m = 0; m < NMODES; ++m) {
    dred[m][tid]          = pr[m];
    dred[NMODES + m][tid] = pi[m];
  }
  __syncthreads();
  {
    const int ch = tid >> 3, p = tid & 7;
    float4 s4 = make_float4(0.f, 0.f, 0.f, 0.f);
    #pragma unroll
    for (int j = 0; j < 8; ++j) {
      const float4 v = *(const float4*)&dred[ch][j * 32 + p * 4];
      s4.x += v.x; s4.y += v.y; s4.z += v.z; s4.w += v.w;
    }
    float ssum = (s4.x + s4.y) + (s4.z + s4.w);
    ssum += __shfl_down(ssum, 4, 64);
    ssum += __shfl_down(ssum, 2, 64);
    ssum += __shfl_down(ssum, 1, 64);
    if (p == 0) Ush[ch] = ssum;
  }
  __syncthreads();

  if (tid < 128) {
    const float invN = 1.0f / (float)EDIM;
    int n = tid >> 6, l = tid & 63;
    int d = n * 16 + (l & 15);
    union { unsigned short u[8]; bf16x8 v; } ph, pl;
    #pragma unroll
    for (int i = 0; i < 8; ++i) {
      int j = (l >> 4) * 8 + i;
      float v;
      if (j < NMODES) {
        int m = j;
        float ofr = Ush[m] * Wmr[m * 32 + d] - Ush[NMODES + m] * Wmi[m * 32 + d];
        v = (m == 0) ? (ofr + b0r[d]) * invN : 2.0f * ofr * invN;
      } else if (j < 31) {
        int m = j - 15;
        float ofi = Ush[m] * Wmi[m * 32 + d] + Ush[NMODES + m] * Wmr[m * 32 + d];
        v = -2.0f * ofi * invN;
      } else {
        v = pb1[d];                          // bias slot (basis == 1)
      }
      f2bf_split(v, ph.u[i], pl.u[i]);
    }
    size_t base = ((size_t)t * 2 + n) * 64 + l;
    *(bf16x8*)&coefFh[base * 8] = ph.v;
    *(bf16x8*)&coefFl[base * 8] = pl.v;
  }
}

// MFMA reconstruction + gelu + fc1, in-place on u. Grid = 4*T_ROWS:
// block (t, cq) covers x in [cq*512, cq*512+512). No LDS. r12 structure with
// explicit 1-deep software pipeline: (bh, bl, uval) for iteration q+1 are
// loaded BEFORE q's MFMA+epilogue, hiding the L2 load latency under compute.
// Persistent state unchanged (r13 lesson); only pipeline regs (+9 VGPR) added.
// pb rides in acc via basis slot 31. LAST: emit bf16 u instead of fp32.
template<int LAST>
__global__ __launch_bounds__(256, 8)
void recon_mfma(float* __restrict__ u,
                unsigned short* __restrict__ u_bf,
                const unsigned short* __restrict__ basFh,
                const unsigned short* __restrict__ basFl,
                const unsigned short* __restrict__ coefFh,
                const unsigned short* __restrict__ coefFl,
                const float* __restrict__ pw1,
                const float* __restrict__ f1w, const float* __restrict__ f1b)
{
  const int t  = blockIdx.x >> 2;
  const int cq = blockIdx.x & 3;
  const int tid = threadIdx.x, lane = tid & 63, w = tid >> 6;
  const int g = lane >> 4, m15 = lane & 15;

  bf16x8 ch[2], cl[2];
  #pragma unroll
  for (int n = 0; n < 2; ++n) {
    size_t base = (((size_t)t * 2 + n) * 64 + lane) * 8;
    ch[n] = *(const bf16x8*)&coefFh[base];
    cl[n] = *(const bf16x8*)&coefFl[base];
  }

  float4 pwv[2], fv[2];
  #pragma unroll
  for (int n = 0; n < 2; ++n) {
    pwv[n] = *(const float4*)&pw1[n * 16 + g * 4];
    fv[n]  = *(const float4*)&f1w[n * 16 + g * 4];
  }
  const float fb = f1b[0];
  float* __restrict__ urow = u + (size_t)t * EDIM;

  const int mt0 = cq * 32 + w * 8;
  bf16x8 bh = *(const bf16x8*)&basFh[((size_t)mt0 * 64 + lane) * 8];
  bf16x8 bl = *(const bf16x8*)&basFl[((size_t)mt0 * 64 + lane) * 8];
  float uval = urow[mt0 * 16 + m15];

  #pragma unroll
  for (int q = 0; q < 8; ++q) {
    const int mt = mt0 + q;
    // prefetch next iteration's operands before consuming current
    bf16x8 bhN, blN; float uvN;
    if (q < 7) {
      const int mtn = mt + 1;
      bhN = *(const bf16x8*)&basFh[((size_t)mtn * 64 + lane) * 8];
      blN = *(const bf16x8*)&basFl[((size_t)mtn * 64 + lane) * 8];
      uvN = urow[mtn * 16 + m15];
    }
    f32x4 acc[2];
    #pragma unroll
    for (int n = 0; n < 2; ++n) {
      f32x4 a = {};
      a = __builtin_amdgcn_mfma_f32_16x16x32_bf16(cl[n], bh, a, 0, 0, 0);
      a = __builtin_amdgcn_mfma_f32_16x16x32_bf16(ch[n], bl, a, 0, 0, 0);
      a = __builtin_amdgcn_mfma_f32_16x16x32_bf16(ch[n], bh, a, 0, 0, 0);
      acc[n] = a;
    }
    const int x = mt * 16 + m15;
    float o = 0.f;
    #pragma unroll
    for (int n = 0; n < 2; ++n) {
      #pragma unroll
      for (int r = 0; r < 4; ++r) {
        float s = fmaf(uval, ((const float*)&pwv[n])[r], acc[n][r]);  // pb in acc
        float s2 = s * s;
        float arg = s * fmaf(0.1029433f, s2, 2.3022082f);   // 2.88539*(0.79788+0.0356774 s^2)
        float e2 = __builtin_amdgcn_exp2f(arg);
        float r1 = __builtin_amdgcn_rcpf(e2 + 1.0f);
        float sf = s * ((const float*)&fv[n])[r];
        o += sf;
        o = fmaf(-sf, r1, o);               // o += sf*(1-r1) == gelu(s)*f
      }
    }
    o += __shfl_xor(o, 16, 64);
    o += __shfl_xor(o, 32, 64);
    if (lane < 16) {
      if (LAST) u_bf[(size_t)t * EDIM + x] = f2bf(o + fb);
      else      urow[x] = o + fb;
    }
    if (q < 7) { bh = bhN; bl = blN; uval = uvN; }
  }
}

extern "C" void kernel_launch(void* const* d_in, const int* in_sizes, int n_in,
                              void* d_out, int out_size, void* d_ws, size_t ws_size,
                              hipStream_t stream)
{
  const float* x    = (const float*)d_in[0];
  const float* W_en = (const float*)d_in[1];
  const float* b_en = (const float*)d_in[2];
  const float* fc0w = (const float*)d_in[3];
  const float* fc0b = (const float*)d_in[4];
  const float* swr  = (const float*)d_in[5];
  const float* swi  = (const float*)d_in[6];
  const float* pww  = (const float*)d_in[7];
  const float* pwb  = (const float*)d_in[8];
  const float* f1w  = (const float*)d_in[9];
  const float* f1b  = (const float*)d_in[10];
  const float* W_de = (const float*)d_in[11];
  const float* b_de = (const float*)d_in[12];
  float* out = (float*)d_out;
  float* ws  = (float*)d_ws;

  float* u    = ws;                                   // 1024*2048
  float* ctab = u + (size_t)T_ROWS * EDIM;            // 2048
  float* stab = ctab + EDIM;                          // 2048
  float* Wmr  = stab + EDIM;                          // 4*16*32
  float* Wmi  = Wmr + NLAYERS * NMODES * 32;          // 4*16*32
  float* b0r  = Wmi + NLAYERS * NMODES * 32;          // 4*32
  float* pw1  = b0r + NLAYERS * 32;                   // 4*32
  float* pb1  = pw1 + NLAYERS * 32;                   // 4*32
  unsigned short* basFh  = (unsigned short*)(pb1 + NLAYERS * 32);   // 128*64*8
  unsigned short* basFl  = basFh + 128 * 64 * 8;                    // 128*64*8
  unsigned short* coefFh = basFl + 128 * 64 * 8;                    // 1024*2*64*8
  unsigned short* coefFl = coefFh + (size_t)T_ROWS * 2 * 64 * 8;
  unsigned short* x_bf   = coefFl + (size_t)T_ROWS * 2 * 64 * 8;    // 1024*1024
  unsigned short* u_bf   = x_bf + (size_t)T_ROWS * IN_DIM;          // 1024*2048
  unsigned short* WenT   = u_bf + (size_t)T_ROWS * EDIM;            // [2048][1024]
  unsigned short* WdeT   = WenT + (size_t)EDIM * IN_DIM;            // [1024][2048]

  setup_all<<<4873, 256, 0, stream>>>(ctab, stab, basFh, basFl, fc0w, fc0b,
                                      swr, swi, pww, pwb, Wmr, Wmi, b0r, pw1, pb1,
                                      W_en, WenT, W_de, WdeT, x, x_bf);

  { dim3 g(EDIM / 64, T_ROWS / 64);
    gemm_mfma<<<g, 256, 0, stream>>>(x_bf, WenT, b_en, u, T_ROWS, EDIM, IN_DIM); }

  for (int l = 0; l < NLAYERS; ++l) {
    dft_coef<<<T_ROWS, 256, 0, stream>>>(u, ctab, stab,
        Wmr + l * NMODES * 32, Wmi + l * NMODES * 32, b0r + l * 32, pb1 + l * 32,
        coefFh, coefFl);
    if (l < NLAYERS - 1)
      recon_mfma<0><<<4 * T_ROWS, 256, 0, stream>>>(u, u_bf, basFh, basFl,
          coefFh, coefFl, pw1 + l * 32, f1w + l * 32, f1b + l);
    else
      recon_mfma<1><<<4 * T_ROWS, 256, 0, stream>>>(u, u_bf, basFh, basFl,
          coefFh, coefFl, pw1 + l * 32, f1w + l * 32, f1b + l);
  }

  { dim3 g(OUT_DIM / 64, T_ROWS / 64);
    gemm_mfma<<<g, 256, 0, stream>>>(u_bf, WdeT, b_de, out, T_ROWS, OUT_DIM, EDIM); }
}

// Round 17
// 218.620 us; speedup vs baseline: 1.0318x; 1.0318x over previous
//
#include <hip/hip_runtime.h>
#include <math.h>

#ifndef M_PI
#define M_PI 3.14159265358979323846
#endif

#define T_ROWS 1024
#define EDIM   2048
#define IN_DIM 1024
#define OUT_DIM 1024
#define NMODES 16
#define NLAYERS 4

typedef __attribute__((ext_vector_type(8))) short bf16x8;
typedef __attribute__((ext_vector_type(4))) float f32x4;

__device__ __forceinline__ unsigned short f2bf(float f) {
  union { float f; unsigned u; } v; v.f = f;
  unsigned r = v.u + 0x7FFFu + ((v.u >> 16) & 1u);  // RNE
  return (unsigned short)(r >> 16);
}
__device__ __forceinline__ float bf2f(unsigned short h) {
  union { unsigned u; float f; } v; v.u = ((unsigned)h) << 16;
  return v.f;
}
__device__ __forceinline__ void f2bf_split(float v, unsigned short& h, unsigned short& l) {
  h = f2bf(v);
  l = f2bf(v - bf2f(h));
}

// B[K][N] fp32 -> BT[N][K] bf16, one 32x32 tile (device helper for setup_all)
__device__ __forceinline__ void transpose_tile(const float* __restrict__ B,
                                               unsigned short* __restrict__ BT,
                                               int K, int N, int k0, int n0, int tid,
                                               float (*tile)[33])
{
  {
    int r = tid >> 3, c4 = (tid & 7) * 4;
    float4 v = *(const float4*)&B[(size_t)(k0 + r) * N + n0 + c4];
    tile[r][c4 + 0] = v.x; tile[r][c4 + 1] = v.y;
    tile[r][c4 + 2] = v.z; tile[r][c4 + 3] = v.w;
  }
  __syncthreads();
  {
    int n = tid >> 3, kq = (tid & 7) * 4;
    ushort4 o;
    o.x = f2bf(tile[kq + 0][n]); o.y = f2bf(tile[kq + 1][n]);
    o.z = f2bf(tile[kq + 2][n]); o.w = f2bf(tile[kq + 3][n]);
    *(ushort4*)&BT[(size_t)(n0 + n) * K + k0 + kq] = o;
  }
}

// Fused setup.
// 0..7: ctab/stab (f64 trig: feeds error-compounding twiddle recurrence)
// 8..263: basF frag table via f32 trig (1-2 ulp << bf16 hi/lo split floor)
// 264: folded weights | 265..2312: WenT | 2313..4360: WdeT | 4361..: x cvt
__global__ __launch_bounds__(256)
void setup_all(float* __restrict__ ctab, float* __restrict__ stab,
               unsigned short* __restrict__ basFh, unsigned short* __restrict__ basFl,
               const float* __restrict__ fc0w, const float* __restrict__ fc0b,
               const float* __restrict__ wr, const float* __restrict__ wi,
               const float* __restrict__ pww, const float* __restrict__ pwb,
               float* __restrict__ Wmr, float* __restrict__ Wmi,
               float* __restrict__ b0r, float* __restrict__ pw1,
               float* __restrict__ pb1,
               const float* __restrict__ W_en, unsigned short* __restrict__ WenT,
               const float* __restrict__ W_de, unsigned short* __restrict__ WdeT,
               const float* __restrict__ x, unsigned short* __restrict__ x_bf)
{
  __shared__ float tile[32][33];
  const int b = blockIdx.x, tid = threadIdx.x;
  if (b < 8) {
    int i = b * 256 + tid;
    double ang = (2.0 * M_PI / (double)EDIM) * (double)i;
    ctab[i] = (float)cos(ang);
    stab[i] = (float)sin(ang);
  } else if (b < 264) {
    int idx = (b - 8) * 256 + tid;            // [0, 65536)
    int mt = idx >> 9;
    int l  = (idx >> 3) & 63;
    int i  = idx & 7;
    int xx = mt * 16 + (l & 15);
    int j  = (l >> 4) * 8 + i;
    float v;
    if (j < 31) {
      int m = (j < NMODES) ? j : (j - 15);
      int ia = (m * xx) & (EDIM - 1);
      float ang = (float)(2.0 * M_PI / (double)EDIM) * (float)ia;
      v = (j < NMODES) ? cosf(ang) : sinf(ang);
    } else {
      v = 1.0f;                               // bias slot
    }
    unsigned short h, lo; f2bf_split(v, h, lo);
    basFh[idx] = h; basFl[idx] = lo;
  } else if (b == 264) {
    if (tid >= NLAYERS * 32) return;
    int l = tid >> 5, d = tid & 31;
    for (int m = 0; m < NMODES; ++m) {
      float sr = 0.f, si = 0.f;
      for (int c = 0; c < 32; ++c) {
        float w0 = fc0w[l * 32 + c];
        size_t base = ((size_t)(l * 32 + c) * 32 + d) * NMODES + m;
        sr += w0 * wr[base];
        si += w0 * wi[base];
      }
      Wmr[(l * NMODES + m) * 32 + d] = sr;
      Wmi[(l * NMODES + m) * 32 + d] = si;
    }
    float sb = 0.f, sp = 0.f, sq = 0.f;
    for (int c = 0; c < 32; ++c) {
      float b0 = fc0b[l * 32 + c];
      float w0 = fc0w[l * 32 + c];
      sb += b0 * wr[((size_t)(l * 32 + c) * 32 + d) * NMODES + 0];
      float pw = pww[(size_t)(l * 32 + c) * 32 + d];
      sp += w0 * pw;
      sq += b0 * pw;
    }
    b0r[l * 32 + d] = (float)EDIM * sb;
    pw1[l * 32 + d] = sp;
    pb1[l * 32 + d] = sq + pwb[l * 32 + d];
  } else if (b < 2313) {
    int tb = b - 265;                         // W_en: K=IN_DIM, N=EDIM
    int n0 = (tb & 63) * 32, k0 = (tb >> 6) * 32;
    transpose_tile(W_en, WenT, IN_DIM, EDIM, k0, n0, tid, tile);
  } else if (b < 4361) {
    int tb = b - 2313;                        // W_de: K=EDIM, N=OUT_DIM
    int n0 = (tb & 31) * 32, k0 = (tb >> 5) * 32;
    transpose_tile(W_de, WdeT, EDIM, OUT_DIM, k0, n0, tid, tile);
  } else {
    size_t i0 = ((size_t)(b - 4361) * 256 + tid) * 8;   // x cvt, 1M elements
    float4 a0 = *(const float4*)&x[i0];
    float4 a1 = *(const float4*)&x[i0 + 4];
    ushort4 o0, o1;
    o0.x = f2bf(a0.x); o0.y = f2bf(a0.y); o0.z = f2bf(a0.z); o0.w = f2bf(a0.w);
    o1.x = f2bf(a1.x); o1.y = f2bf(a1.y); o1.z = f2bf(a1.z); o1.w = f2bf(a1.w);
    *(ushort4*)&x_bf[i0]     = o0;
    *(ushort4*)&x_bf[i0 + 4] = o1;
  }
}

// C[M][N] = A[M][K](bf16) @ BT[N][K](bf16)^T + bias. 64x64 tile, BK=64.
// Double-buffered LDS + register prefetch (r14 structure, best measured).
#define BKK 64
__global__ __launch_bounds__(256)
void gemm_mfma(const unsigned short* __restrict__ A, const unsigned short* __restrict__ BT,
               const float* __restrict__ bias, float* __restrict__ C,
               int M, int N, int K)
{
  __shared__ __align__(16) unsigned short Asb[2][64 * BKK];
  __shared__ __align__(16) unsigned short Bsb[2][64 * BKK];
  const int tid = threadIdx.x;
  const int bm = blockIdx.y * 64, bn = blockIdx.x * 64;
  const int lane = tid & 63, wave = tid >> 6;
  const int wr = wave >> 1, wc = wave & 1;

  const int srow = tid >> 2;          // 0..63
  const int skq  = tid & 3;           // 16-k chunk

  f32x4 acc[2][2] = {};

  const unsigned short* aRow = A + (size_t)(bm + srow) * K + skq * 16;
  const unsigned short* bRow = BT + (size_t)(bn + srow) * K + skq * 16;

  int slot0 = (skq * 2 + 0) ^ ((srow >> 1) & 7);
  int slot1 = (skq * 2 + 1) ^ ((srow >> 1) & 7);

  bf16x8 pa0, pa1, pb0, pb1v;
  pa0 = *(const bf16x8*)(aRow + 0);
  pa1 = *(const bf16x8*)(aRow + 8);
  pb0 = *(const bf16x8*)(bRow + 0);
  pb1v = *(const bf16x8*)(bRow + 8);
  *(bf16x8*)&Asb[0][srow * BKK + slot0 * 8] = pa0;
  *(bf16x8*)&Asb[0][srow * BKK + slot1 * 8] = pa1;
  *(bf16x8*)&Bsb[0][srow * BKK + slot0 * 8] = pb0;
  *(bf16x8*)&Bsb[0][srow * BKK + slot1 * 8] = pb1v;

  int cur = 0;
  for (int k0 = 0; k0 < K; k0 += BKK) {
    __syncthreads();                         // buf[cur] ready
    const bool more = (k0 + BKK) < K;
    if (more) {
      pa0 = *(const bf16x8*)(aRow + k0 + BKK);
      pa1 = *(const bf16x8*)(aRow + k0 + BKK + 8);
      pb0 = *(const bf16x8*)(bRow + k0 + BKK);
      pb1v = *(const bf16x8*)(bRow + k0 + BKK + 8);
    }
    #pragma unroll
    for (int s = 0; s < 2; ++s) {
      int kb = s * 4 + (lane >> 4);
      bf16x8 a[2], b[2];
      #pragma unroll
      for (int i = 0; i < 2; ++i) {
        int ar = wr * 32 + i * 16 + (lane & 15);
        a[i] = *(const bf16x8*)&Asb[cur][ar * BKK + (kb ^ ((ar >> 1) & 7)) * 8];
        int br = wc * 32 + i * 16 + (lane & 15);
        b[i] = *(const bf16x8*)&Bsb[cur][br * BKK + (kb ^ ((br >> 1) & 7)) * 8];
      }
      #pragma unroll
      for (int i = 0; i < 2; ++i)
        #pragma unroll
        for (int j = 0; j < 2; ++j)
          acc[i][j] = __builtin_amdgcn_mfma_f32_16x16x32_bf16(a[i], b[j], acc[i][j], 0, 0, 0);
    }
    if (more) {
      const int nxt = cur ^ 1;
      *(bf16x8*)&Asb[nxt][srow * BKK + slot0 * 8] = pa0;
      *(bf16x8*)&Asb[nxt][srow * BKK + slot1 * 8] = pa1;
      *(bf16x8*)&Bsb[nxt][srow * BKK + slot0 * 8] = pb0;
      *(bf16x8*)&Bsb[nxt][srow * BKK + slot1 * 8] = pb1v;
    }
    cur ^= 1;
  }

  #pragma unroll
  for (int j = 0; j < 2; ++j) {
    int col = bn + wc * 32 + j * 16 + (lane & 15);
    float bz = bias[col];
    #pragma unroll
    for (int i = 0; i < 2; ++i)
      #pragma unroll
      for (int r = 0; r < 4; ++r) {
        int row = bm + wr * 32 + i * 16 + (lane >> 4) * 4 + r;
        C[(size_t)row * N + col] = acc[i][j][r] + bz;
      }
  }
}

// 16-mode DFT per row (twiddle recurrence, x<->x+1024 parity fold) + mode mix
// -> bf16 hi/lo fragments; slot31 = pb1. LDS two-phase reduce (r12 structure).
__global__ __launch_bounds__(256)
void dft_coef(const float* __restrict__ u,
              const float* __restrict__ ctab, const float* __restrict__ stab,
              const float* __restrict__ Wmr, const float* __restrict__ Wmi,
              const float* __restrict__ b0r, const float* __restrict__ pb1,
              unsigned short* __restrict__ coefFh, unsigned short* __restrict__ coefFl)
{
  const int t = blockIdx.x, tid = threadIdx.x;
  __shared__ float dred[32][264];
  __shared__ float Ush[32];

  float pr[NMODES], pi[NMODES];
  #pragma unroll
  for (int m = 0; m < NMODES; ++m) { pr[m] = 0.f; pi[m] = 0.f; }
  #pragma unroll
  for (int it = 0; it < 4; ++it) {
    const int x = tid + it * 256;
    const float v0 = u[(size_t)t * EDIM + x];
    const float v1 = u[(size_t)t * EDIM + x + 1024];
    const float ve = v0 + v1, vo = v0 - v1;
    const float cx = ctab[x], sx = stab[x];
    float c = 1.f, s = 0.f;
    #pragma unroll
    for (int m = 0; m < NMODES; ++m) {
      const float vsel = (m & 1) ? vo : ve;
      pr[m] += vsel * c;
      pi[m] -= vsel * s;
      float cn = c * cx - s * sx;
      s = s * cx + c * sx;
      c = cn;
    }
  }
  #pragma unroll
  for (int m = 0; m < NMODES; ++m) {
    dred[m][tid]          = pr[m];
    dred[NMODES + m][tid] = pi[m];
  }
  __syncthreads();
  {
    const int ch = tid >> 3, p = tid & 7;
    float4 s4 = make_float4(0.f, 0.f, 0.f, 0.f);
    #pragma unroll
    for (int j = 0; j < 8; ++j) {
      const float4 v = *(const float4*)&dred[ch][j * 32 + p * 4];
      s4.x += v.x; s4.y += v.y; s4.z += v.z; s4.w += v.w;
    }
    float ssum = (s4.x + s4.y) + (s4.z + s4.w);
    ssum += __shfl_down(ssum, 4, 64);
    ssum += __shfl_down(ssum, 2, 64);
    ssum += __shfl_down(ssum, 1, 64);
    if (p == 0) Ush[ch] = ssum;
  }
  __syncthreads();

  if (tid < 128) {
    const float invN = 1.0f / (float)EDIM;
    int n = tid >> 6, l = tid & 63;
    int d = n * 16 + (l & 15);
    union { unsigned short u[8]; bf16x8 v; } ph, pl;
    #pragma unroll
    for (int i = 0; i < 8; ++i) {
      int j = (l >> 4) * 8 + i;
      float v;
      if (j < NMODES) {
        int m = j;
        float ofr = Ush[m] * Wmr[m * 32 + d] - Ush[NMODES + m] * Wmi[m * 32 + d];
        v = (m == 0) ? (ofr + b0r[d]) * invN : 2.0f * ofr * invN;
      } else if (j < 31) {
        int m = j - 15;
        float ofi = Ush[m] * Wmi[m * 32 + d] + Ush[NMODES + m] * Wmr[m * 32 + d];
        v = -2.0f * ofi * invN;
      } else {
        v = pb1[d];                          // bias slot (basis == 1)
      }
      f2bf_split(v, ph.u[i], pl.u[i]);
    }
    size_t base = ((size_t)t * 2 + n) * 64 + l;
    *(bf16x8*)&coefFh[base * 8] = ph.v;
    *(bf16x8*)&coefFl[base * 8] = pl.v;
  }
}

// MFMA reconstruction + gelu + fc1, in-place on u. Grid = 4*T_ROWS:
// block (t, cq) covers x in [cq*512, cq*512+512). No LDS. r12 structure
// (r15's explicit prefetch was neutral -> removed). Algebraic gelu tail:
// gelu(s)*f = s(1-r1)*f via t=fmaf(-s,r1,s); o=fmaf(t,f,o) — 6 VALU + 2
// trans per element (was 8+2). pb rides in acc via basis slot 31.
// LAST: emit bf16 u (decoder GEMM input) instead of fp32.
template<int LAST>
__global__ __launch_bounds__(256, 8)
void recon_mfma(float* __restrict__ u,
                unsigned short* __restrict__ u_bf,
                const unsigned short* __restrict__ basFh,
                const unsigned short* __restrict__ basFl,
                const unsigned short* __restrict__ coefFh,
                const unsigned short* __restrict__ coefFl,
                const float* __restrict__ pw1,
                const float* __restrict__ f1w, const float* __restrict__ f1b)
{
  const int t  = blockIdx.x >> 2;
  const int cq = blockIdx.x & 3;
  const int tid = threadIdx.x, lane = tid & 63, w = tid >> 6;
  const int g = lane >> 4, m15 = lane & 15;

  bf16x8 ch[2], cl[2];
  #pragma unroll
  for (int n = 0; n < 2; ++n) {
    size_t base = (((size_t)t * 2 + n) * 64 + lane) * 8;
    ch[n] = *(const bf16x8*)&coefFh[base];
    cl[n] = *(const bf16x8*)&coefFl[base];
  }

  float4 pwv[2], fv[2];
  #pragma unroll
  for (int n = 0; n < 2; ++n) {
    pwv[n] = *(const float4*)&pw1[n * 16 + g * 4];
    fv[n]  = *(const float4*)&f1w[n * 16 + g * 4];
  }
  const float fb = f1b[0];
  float* __restrict__ urow = u + (size_t)t * EDIM;

  #pragma unroll
  for (int q = 0; q < 8; ++q) {
    const int mt = cq * 32 + w * 8 + q;
    bf16x8 bh = *(const bf16x8*)&basFh[((size_t)mt * 64 + lane) * 8];
    bf16x8 bl = *(const bf16x8*)&basFl[((size_t)mt * 64 + lane) * 8];
    f32x4 acc[2];
    #pragma unroll
    for (int n = 0; n < 2; ++n) {
      f32x4 a = {};
      a = __builtin_amdgcn_mfma_f32_16x16x32_bf16(cl[n], bh, a, 0, 0, 0);
      a = __builtin_amdgcn_mfma_f32_16x16x32_bf16(ch[n], bl, a, 0, 0, 0);
      a = __builtin_amdgcn_mfma_f32_16x16x32_bf16(ch[n], bh, a, 0, 0, 0);
      acc[n] = a;
    }
    const int x = mt * 16 + m15;
    const float uval = urow[x];
    float o = 0.f;
    #pragma unroll
    for (int n = 0; n < 2; ++n) {
      #pragma unroll
      for (int r = 0; r < 4; ++r) {
        float s = fmaf(uval, ((const float*)&pwv[n])[r], acc[n][r]);  // pb in acc
        float s2 = s * s;
        float arg = s * fmaf(0.1029433f, s2, 2.3022082f);   // 2.88539*(0.79788+0.0356774 s^2)
        float e2 = __builtin_amdgcn_exp2f(arg);
        float r1 = __builtin_amdgcn_rcpf(e2 + 1.0f);
        float tgl = fmaf(-s, r1, s);                        // s*(1-r1) == gelu(s)
        o = fmaf(tgl, ((const float*)&fv[n])[r], o);
      }
    }
    o += __shfl_xor(o, 16, 64);
    o += __shfl_xor(o, 32, 64);
    if (lane < 16) {
      if (LAST) u_bf[(size_t)t * EDIM + x] = f2bf(o + fb);
      else      urow[x] = o + fb;
    }
  }
}

extern "C" void kernel_launch(void* const* d_in, const int* in_sizes, int n_in,
                              void* d_out, int out_size, void* d_ws, size_t ws_size,
                              hipStream_t stream)
{
  const float* x    = (const float*)d_in[0];
  const float* W_en = (const float*)d_in[1];
  const float* b_en = (const float*)d_in[2];
  const float* fc0w = (const float*)d_in[3];
  const float* fc0b = (const float*)d_in[4];
  const float* swr  = (const float*)d_in[5];
  const float* swi  = (const float*)d_in[6];
  const float* pww  = (const float*)d_in[7];
  const float* pwb  = (const float*)d_in[8];
  const float* f1w  = (const float*)d_in[9];
  const float* f1b  = (const float*)d_in[10];
  const float* W_de = (const float*)d_in[11];
  const float* b_de = (const float*)d_in[12];
  float* out = (float*)d_out;
  float* ws  = (float*)d_ws;

  float* u    = ws;                                   // 1024*2048
  float* ctab = u + (size_t)T_ROWS * EDIM;            // 2048
  float* stab = ctab + EDIM;                          // 2048
  float* Wmr  = stab + EDIM;                          // 4*16*32
  float* Wmi  = Wmr + NLAYERS * NMODES * 32;          // 4*16*32
  float* b0r  = Wmi + NLAYERS * NMODES * 32;          // 4*32
  float* pw1  = b0r + NLAYERS * 32;                   // 4*32
  float* pb1  = pw1 + NLAYERS * 32;                   // 4*32
  unsigned short* basFh  = (unsigned short*)(pb1 + NLAYERS * 32);   // 128*64*8
  unsigned short* basFl  = basFh + 128 * 64 * 8;                    // 128*64*8
  unsigned short* coefFh = basFl + 128 * 64 * 8;                    // 1024*2*64*8
  unsigned short* coefFl = coefFh + (size_t)T_ROWS * 2 * 64 * 8;
  unsigned short* x_bf   = coefFl + (size_t)T_ROWS * 2 * 64 * 8;    // 1024*1024
  unsigned short* u_bf   = x_bf + (size_t)T_ROWS * IN_DIM;          // 1024*2048
  unsigned short* WenT   = u_bf + (size_t)T_ROWS * EDIM;            // [2048][1024]
  unsigned short* WdeT   = WenT + (size_t)EDIM * IN_DIM;            // [1024][2048]

  setup_all<<<4873, 256, 0, stream>>>(ctab, stab, basFh, basFl, fc0w, fc0b,
                                      swr, swi, pww, pwb, Wmr, Wmi, b0r, pw1, pb1,
                                      W_en, WenT, W_de, WdeT, x, x_bf);

  { dim3 g(EDIM / 64, T_ROWS / 64);
    gemm_mfma<<<g, 256, 0, stream>>>(x_bf, WenT, b_en, u, T_ROWS, EDIM, IN_DIM); }

  for (int l = 0; l < NLAYERS; ++l) {
    dft_coef<<<T_ROWS, 256, 0, stream>>>(u, ctab, stab,
        Wmr + l * NMODES * 32, Wmi + l * NMODES * 32, b0r + l * 32, pb1 + l * 32,
        coefFh, coefFl);
    if (l < NLAYERS - 1)
      recon_mfma<0><<<4 * T_ROWS, 256, 0, stream>>>(u, u_bf, basFh, basFl,
          coefFh, coefFl, pw1 + l * 32, f1w + l * 32, f1b + l);
    else
      recon_mfma<1><<<4 * T_ROWS, 256, 0, stream>>>(u, u_bf, basFh, basFl,
          coefFh, coefFl, pw1 + l * 32, f1w + l * 32, f1b + l);
  }

  { dim3 g(OUT_DIM / 64, T_ROWS / 64);
    gemm_mfma<<<g, 256, 0, stream>>>(u_bf, WdeT, b_de, out, T_ROWS, OUT_DIM, EDIM); }
}

// Round 18
// 216.358 us; speedup vs baseline: 1.0426x; 1.0105x over previous
//
#include <hip/hip_runtime.h>
#include <math.h>

#ifndef M_PI
#define M_PI 3.14159265358979323846
#endif

#define T_ROWS 1024
#define EDIM   2048
#define IN_DIM 1024
#define OUT_DIM 1024
#define NMODES 16
#define NLAYERS 4

typedef __attribute__((ext_vector_type(8))) short bf16x8;
typedef __attribute__((ext_vector_type(4))) float f32x4;
typedef __attribute__((ext_vector_type(2))) float f32x2;

__device__ __forceinline__ unsigned short f2bf(float f) {
  union { float f; unsigned u; } v; v.f = f;
  unsigned r = v.u + 0x7FFFu + ((v.u >> 16) & 1u);  // RNE
  return (unsigned short)(r >> 16);
}
__device__ __forceinline__ float bf2f(unsigned short h) {
  union { unsigned u; float f; } v; v.u = ((unsigned)h) << 16;
  return v.f;
}
__device__ __forceinline__ void f2bf_split(float v, unsigned short& h, unsigned short& l) {
  h = f2bf(v);
  l = f2bf(v - bf2f(h));
}

// B[K][N] fp32 -> BT[N][K] bf16, one 32x32 tile (device helper for setup_all)
__device__ __forceinline__ void transpose_tile(const float* __restrict__ B,
                                               unsigned short* __restrict__ BT,
                                               int K, int N, int k0, int n0, int tid,
                                               float (*tile)[33])
{
  {
    int r = tid >> 3, c4 = (tid & 7) * 4;
    float4 v = *(const float4*)&B[(size_t)(k0 + r) * N + n0 + c4];
    tile[r][c4 + 0] = v.x; tile[r][c4 + 1] = v.y;
    tile[r][c4 + 2] = v.z; tile[r][c4 + 3] = v.w;
  }
  __syncthreads();
  {
    int n = tid >> 3, kq = (tid & 7) * 4;
    ushort4 o;
    o.x = f2bf(tile[kq + 0][n]); o.y = f2bf(tile[kq + 1][n]);
    o.z = f2bf(tile[kq + 2][n]); o.w = f2bf(tile[kq + 3][n]);
    *(ushort4*)&BT[(size_t)(n0 + n) * K + k0 + kq] = o;
  }
}

// Fused setup.
// 0..7: ctab/stab (f64 trig: feeds error-compounding twiddle recurrence)
// 8..263: basF frag table via f32 trig (1-2 ulp << bf16 hi/lo split floor)
// 264: folded weights | 265..2312: WenT | 2313..4360: WdeT | 4361..: x cvt
__global__ __launch_bounds__(256)
void setup_all(float* __restrict__ ctab, float* __restrict__ stab,
               unsigned short* __restrict__ basFh, unsigned short* __restrict__ basFl,
               const float* __restrict__ fc0w, const float* __restrict__ fc0b,
               const float* __restrict__ wr, const float* __restrict__ wi,
               const float* __restrict__ pww, const float* __restrict__ pwb,
               float* __restrict__ Wmr, float* __restrict__ Wmi,
               float* __restrict__ b0r, float* __restrict__ pw1,
               float* __restrict__ pb1,
               const float* __restrict__ W_en, unsigned short* __restrict__ WenT,
               const float* __restrict__ W_de, unsigned short* __restrict__ WdeT,
               const float* __restrict__ x, unsigned short* __restrict__ x_bf)
{
  __shared__ float tile[32][33];
  const int b = blockIdx.x, tid = threadIdx.x;
  if (b < 8) {
    int i = b * 256 + tid;
    double ang = (2.0 * M_PI / (double)EDIM) * (double)i;
    ctab[i] = (float)cos(ang);
    stab[i] = (float)sin(ang);
  } else if (b < 264) {
    int idx = (b - 8) * 256 + tid;            // [0, 65536)
    int mt = idx >> 9;
    int l  = (idx >> 3) & 63;
    int i  = idx & 7;
    int xx = mt * 16 + (l & 15);
    int j  = (l >> 4) * 8 + i;
    float v;
    if (j < 31) {
      int m = (j < NMODES) ? j : (j - 15);
      int ia = (m * xx) & (EDIM - 1);
      float ang = (float)(2.0 * M_PI / (double)EDIM) * (float)ia;
      v = (j < NMODES) ? cosf(ang) : sinf(ang);
    } else {
      v = 1.0f;                               // bias slot
    }
    unsigned short h, lo; f2bf_split(v, h, lo);
    basFh[idx] = h; basFl[idx] = lo;
  } else if (b == 264) {
    if (tid >= NLAYERS * 32) return;
    int l = tid >> 5, d = tid & 31;
    for (int m = 0; m < NMODES; ++m) {
      float sr = 0.f, si = 0.f;
      for (int c = 0; c < 32; ++c) {
        float w0 = fc0w[l * 32 + c];
        size_t base = ((size_t)(l * 32 + c) * 32 + d) * NMODES + m;
        sr += w0 * wr[base];
        si += w0 * wi[base];
      }
      Wmr[(l * NMODES + m) * 32 + d] = sr;
      Wmi[(l * NMODES + m) * 32 + d] = si;
    }
    float sb = 0.f, sp = 0.f, sq = 0.f;
    for (int c = 0; c < 32; ++c) {
      float b0 = fc0b[l * 32 + c];
      float w0 = fc0w[l * 32 + c];
      sb += b0 * wr[((size_t)(l * 32 + c) * 32 + d) * NMODES + 0];
      float pw = pww[(size_t)(l * 32 + c) * 32 + d];
      sp += w0 * pw;
      sq += b0 * pw;
    }
    b0r[l * 32 + d] = (float)EDIM * sb;
    pw1[l * 32 + d] = sp;
    pb1[l * 32 + d] = sq + pwb[l * 32 + d];
  } else if (b < 2313) {
    int tb = b - 265;                         // W_en: K=IN_DIM, N=EDIM
    int n0 = (tb & 63) * 32, k0 = (tb >> 6) * 32;
    transpose_tile(W_en, WenT, IN_DIM, EDIM, k0, n0, tid, tile);
  } else if (b < 4361) {
    int tb = b - 2313;                        // W_de: K=EDIM, N=OUT_DIM
    int n0 = (tb & 31) * 32, k0 = (tb >> 5) * 32;
    transpose_tile(W_de, WdeT, EDIM, OUT_DIM, k0, n0, tid, tile);
  } else {
    size_t i0 = ((size_t)(b - 4361) * 256 + tid) * 8;   // x cvt, 1M elements
    float4 a0 = *(const float4*)&x[i0];
    float4 a1 = *(const float4*)&x[i0 + 4];
    ushort4 o0, o1;
    o0.x = f2bf(a0.x); o0.y = f2bf(a0.y); o0.z = f2bf(a0.z); o0.w = f2bf(a0.w);
    o1.x = f2bf(a1.x); o1.y = f2bf(a1.y); o1.z = f2bf(a1.z); o1.w = f2bf(a1.w);
    *(ushort4*)&x_bf[i0]     = o0;
    *(ushort4*)&x_bf[i0 + 4] = o1;
  }
}

// C[M][N] = A[M][K](bf16) @ BT[N][K](bf16)^T + bias. 64x64 tile, BK=64.
// Double-buffered LDS + register prefetch (r14 structure, best measured).
#define BKK 64
__global__ __launch_bounds__(256)
void gemm_mfma(const unsigned short* __restrict__ A, const unsigned short* __restrict__ BT,
               const float* __restrict__ bias, float* __restrict__ C,
               int M, int N, int K)
{
  __shared__ __align__(16) unsigned short Asb[2][64 * BKK];
  __shared__ __align__(16) unsigned short Bsb[2][64 * BKK];
  const int tid = threadIdx.x;
  const int bm = blockIdx.y * 64, bn = blockIdx.x * 64;
  const int lane = tid & 63, wave = tid >> 6;
  const int wr = wave >> 1, wc = wave & 1;

  const int srow = tid >> 2;          // 0..63
  const int skq  = tid & 3;           // 16-k chunk

  f32x4 acc[2][2] = {};

  const unsigned short* aRow = A + (size_t)(bm + srow) * K + skq * 16;
  const unsigned short* bRow = BT + (size_t)(bn + srow) * K + skq * 16;

  int slot0 = (skq * 2 + 0) ^ ((srow >> 1) & 7);
  int slot1 = (skq * 2 + 1) ^ ((srow >> 1) & 7);

  bf16x8 pa0, pa1, pb0, pb1v;
  pa0 = *(const bf16x8*)(aRow + 0);
  pa1 = *(const bf16x8*)(aRow + 8);
  pb0 = *(const bf16x8*)(bRow + 0);
  pb1v = *(const bf16x8*)(bRow + 8);
  *(bf16x8*)&Asb[0][srow * BKK + slot0 * 8] = pa0;
  *(bf16x8*)&Asb[0][srow * BKK + slot1 * 8] = pa1;
  *(bf16x8*)&Bsb[0][srow * BKK + slot0 * 8] = pb0;
  *(bf16x8*)&Bsb[0][srow * BKK + slot1 * 8] = pb1v;

  int cur = 0;
  for (int k0 = 0; k0 < K; k0 += BKK) {
    __syncthreads();                         // buf[cur] ready
    const bool more = (k0 + BKK) < K;
    if (more) {
      pa0 = *(const bf16x8*)(aRow + k0 + BKK);
      pa1 = *(const bf16x8*)(aRow + k0 + BKK + 8);
      pb0 = *(const bf16x8*)(bRow + k0 + BKK);
      pb1v = *(const bf16x8*)(bRow + k0 + BKK + 8);
    }
    #pragma unroll
    for (int s = 0; s < 2; ++s) {
      int kb = s * 4 + (lane >> 4);
      bf16x8 a[2], b[2];
      #pragma unroll
      for (int i = 0; i < 2; ++i) {
        int ar = wr * 32 + i * 16 + (lane & 15);
        a[i] = *(const bf16x8*)&Asb[cur][ar * BKK + (kb ^ ((ar >> 1) & 7)) * 8];
        int br = wc * 32 + i * 16 + (lane & 15);
        b[i] = *(const bf16x8*)&Bsb[cur][br * BKK + (kb ^ ((br >> 1) & 7)) * 8];
      }
      #pragma unroll
      for (int i = 0; i < 2; ++i)
        #pragma unroll
        for (int j = 0; j < 2; ++j)
          acc[i][j] = __builtin_amdgcn_mfma_f32_16x16x32_bf16(a[i], b[j], acc[i][j], 0, 0, 0);
    }
    if (more) {
      const int nxt = cur ^ 1;
      *(bf16x8*)&Asb[nxt][srow * BKK + slot0 * 8] = pa0;
      *(bf16x8*)&Asb[nxt][srow * BKK + slot1 * 8] = pa1;
      *(bf16x8*)&Bsb[nxt][srow * BKK + slot0 * 8] = pb0;
      *(bf16x8*)&Bsb[nxt][srow * BKK + slot1 * 8] = pb1v;
    }
    cur ^= 1;
  }

  #pragma unroll
  for (int j = 0; j < 2; ++j) {
    int col = bn + wc * 32 + j * 16 + (lane & 15);
    float bz = bias[col];
    #pragma unroll
    for (int i = 0; i < 2; ++i)
      #pragma unroll
      for (int r = 0; r < 4; ++r) {
        int row = bm + wr * 32 + i * 16 + (lane >> 4) * 4 + r;
        C[(size_t)row * N + col] = acc[i][j][r] + bz;
      }
  }
}

// 16-mode DFT per row (twiddle recurrence, x<->x+1024 parity fold) + mode mix
// -> bf16 hi/lo fragments; slot31 = pb1. LDS two-phase reduce (r12 structure).
__global__ __launch_bounds__(256)
void dft_coef(const float* __restrict__ u,
              const float* __restrict__ ctab, const float* __restrict__ stab,
              const float* __restrict__ Wmr, const float* __restrict__ Wmi,
              const float* __restrict__ b0r, const float* __restrict__ pb1,
              unsigned short* __restrict__ coefFh, unsigned short* __restrict__ coefFl)
{
  const int t = blockIdx.x, tid = threadIdx.x;
  __shared__ float dred[32][264];
  __shared__ float Ush[32];

  float pr[NMODES], pi[NMODES];
  #pragma unroll
  for (int m = 0; m < NMODES; ++m) { pr[m] = 0.f; pi[m] = 0.f; }
  #pragma unroll
  for (int it = 0; it < 4; ++it) {
    const int x = tid + it * 256;
    const float v0 = u[(size_t)t * EDIM + x];
    const float v1 = u[(size_t)t * EDIM + x + 1024];
    const float ve = v0 + v1, vo = v0 - v1;
    const float cx = ctab[x], sx = stab[x];
    float c = 1.f, s = 0.f;
    #pragma unroll
    for (int m = 0; m < NMODES; ++m) {
      const float vsel = (m & 1) ? vo : ve;
      pr[m] += vsel * c;
      pi[m] -= vsel * s;
      float cn = c * cx - s * sx;
      s = s * cx + c * sx;
      c = cn;
    }
  }
  #pragma unroll
  for (int m = 0; m < NMODES; ++m) {
    dred[m][tid]          = pr[m];
    dred[NMODES + m][tid] = pi[m];
  }
  __syncthreads();
  {
    const int ch = tid >> 3, p = tid & 7;
    float4 s4 = make_float4(0.f, 0.f, 0.f, 0.f);
    #pragma unroll
    for (int j = 0; j < 8; ++j) {
      const float4 v = *(const float4*)&dred[ch][j * 32 + p * 4];
      s4.x += v.x; s4.y += v.y; s4.z += v.z; s4.w += v.w;
    }
    float ssum = (s4.x + s4.y) + (s4.z + s4.w);
    ssum += __shfl_down(ssum, 4, 64);
    ssum += __shfl_down(ssum, 2, 64);
    ssum += __shfl_down(ssum, 1, 64);
    if (p == 0) Ush[ch] = ssum;
  }
  __syncthreads();

  if (tid < 128) {
    const float invN = 1.0f / (float)EDIM;
    int n = tid >> 6, l = tid & 63;
    int d = n * 16 + (l & 15);
    union { unsigned short u[8]; bf16x8 v; } ph, pl;
    #pragma unroll
    for (int i = 0; i < 8; ++i) {
      int j = (l >> 4) * 8 + i;
      float v;
      if (j < NMODES) {
        int m = j;
        float ofr = Ush[m] * Wmr[m * 32 + d] - Ush[NMODES + m] * Wmi[m * 32 + d];
        v = (m == 0) ? (ofr + b0r[d]) * invN : 2.0f * ofr * invN;
      } else if (j < 31) {
        int m = j - 15;
        float ofi = Ush[m] * Wmi[m * 32 + d] + Ush[NMODES + m] * Wmr[m * 32 + d];
        v = -2.0f * ofi * invN;
      } else {
        v = pb1[d];                          // bias slot (basis == 1)
      }
      f2bf_split(v, ph.u[i], pl.u[i]);
    }
    size_t base = ((size_t)t * 2 + n) * 64 + l;
    *(bf16x8*)&coefFh[base * 8] = ph.v;
    *(bf16x8*)&coefFl[base * 8] = pl.v;
  }
}

// MFMA reconstruction + gelu + fc1, in-place on u. Grid = 4*T_ROWS:
// block (t, cq) covers x in [cq*512, cq*512+512). No LDS. r12 structure.
// Epilogue in packed f32x2 arithmetic (v_pk_fma_f32/v_pk_mul_f32 VOP3P):
// halves VALU instruction count of the dominant gelu cost; exp2/rcp stay
// scalar (no packed trans). Packed fma is IEEE-identical; only final
// accumulation order changes (even/odd split + one add).
// pb rides in acc via basis slot 31. LAST: emit bf16 u instead of fp32.
template<int LAST>
__global__ __launch_bounds__(256, 8)
void recon_mfma(float* __restrict__ u,
                unsigned short* __restrict__ u_bf,
                const unsigned short* __restrict__ basFh,
                const unsigned short* __restrict__ basFl,
                const unsigned short* __restrict__ coefFh,
                const unsigned short* __restrict__ coefFl,
                const float* __restrict__ pw1,
                const float* __restrict__ f1w, const float* __restrict__ f1b)
{
  const int t  = blockIdx.x >> 2;
  const int cq = blockIdx.x & 3;
  const int tid = threadIdx.x, lane = tid & 63, w = tid >> 6;
  const int g = lane >> 4, m15 = lane & 15;

  bf16x8 ch[2], cl[2];
  #pragma unroll
  for (int n = 0; n < 2; ++n) {
    size_t base = (((size_t)t * 2 + n) * 64 + lane) * 8;
    ch[n] = *(const bf16x8*)&coefFh[base];
    cl[n] = *(const bf16x8*)&coefFl[base];
  }

  // per-lane epilogue constants as f32x2 pairs: d = n*16 + g*4 + {2p, 2p+1}
  f32x2 pw2[2][2], fv2[2][2];
  #pragma unroll
  for (int n = 0; n < 2; ++n) {
    float4 pv = *(const float4*)&pw1[n * 16 + g * 4];
    float4 fv = *(const float4*)&f1w[n * 16 + g * 4];
    pw2[n][0] = (f32x2){pv.x, pv.y}; pw2[n][1] = (f32x2){pv.z, pv.w};
    fv2[n][0] = (f32x2){fv.x, fv.y}; fv2[n][1] = (f32x2){fv.z, fv.w};
  }
  const float fb = f1b[0];
  float* __restrict__ urow = u + (size_t)t * EDIM;

  const f32x2 kC1 = {0.1029433f, 0.1029433f};
  const f32x2 kC0 = {2.3022082f, 2.3022082f};
  const f32x2 kOne = {1.0f, 1.0f};

  #pragma unroll
  for (int q = 0; q < 8; ++q) {
    const int mt = cq * 32 + w * 8 + q;
    bf16x8 bh = *(const bf16x8*)&basFh[((size_t)mt * 64 + lane) * 8];
    bf16x8 bl = *(const bf16x8*)&basFl[((size_t)mt * 64 + lane) * 8];
    f32x4 acc[2];
    #pragma unroll
    for (int n = 0; n < 2; ++n) {
      f32x4 a = {};
      a = __builtin_amdgcn_mfma_f32_16x16x32_bf16(cl[n], bh, a, 0, 0, 0);
      a = __builtin_amdgcn_mfma_f32_16x16x32_bf16(ch[n], bl, a, 0, 0, 0);
      a = __builtin_amdgcn_mfma_f32_16x16x32_bf16(ch[n], bh, a, 0, 0, 0);
      acc[n] = a;
    }
    const int x = mt * 16 + m15;
    const float uval = urow[x];
    const f32x2 u2 = {uval, uval};
    f32x2 o2 = {0.f, 0.f};
    #pragma unroll
    for (int n = 0; n < 2; ++n) {
      #pragma unroll
      for (int p = 0; p < 2; ++p) {
        f32x2 av = {acc[n][2 * p], acc[n][2 * p + 1]};
        f32x2 s  = __builtin_elementwise_fma(u2, pw2[n][p], av);   // pb in acc
        f32x2 s2 = s * s;
        f32x2 tt = __builtin_elementwise_fma(s2, kC1, kC0);
        f32x2 arg = s * tt;          // 2.88539*2*(0.79788 s + 0.0356774 s^3)
        f32x2 e;
        e.x = __builtin_amdgcn_exp2f(arg.x);
        e.y = __builtin_amdgcn_exp2f(arg.y);
        f32x2 d = e + kOne;
        f32x2 r;
        r.x = __builtin_amdgcn_rcpf(d.x);
        r.y = __builtin_amdgcn_rcpf(d.y);
        f32x2 tgl = __builtin_elementwise_fma(-s, r, s);           // gelu(s)
        o2 = __builtin_elementwise_fma(tgl, fv2[n][p], o2);
      }
    }
    float o = o2.x + o2.y;
    o += __shfl_xor(o, 16, 64);
    o += __shfl_xor(o, 32, 64);
    if (lane < 16) {
      if (LAST) u_bf[(size_t)t * EDIM + x] = f2bf(o + fb);
      else      urow[x] = o + fb;
    }
  }
}

extern "C" void kernel_launch(void* const* d_in, const int* in_sizes, int n_in,
                              void* d_out, int out_size, void* d_ws, size_t ws_size,
                              hipStream_t stream)
{
  const float* x    = (const float*)d_in[0];
  const float* W_en = (const float*)d_in[1];
  const float* b_en = (const float*)d_in[2];
  const float* fc0w = (const float*)d_in[3];
  const float* fc0b = (const float*)d_in[4];
  const float* swr  = (const float*)d_in[5];
  const float* swi  = (const float*)d_in[6];
  const float* pww  = (const float*)d_in[7];
  const float* pwb  = (const float*)d_in[8];
  const float* f1w  = (const float*)d_in[9];
  const float* f1b  = (const float*)d_in[10];
  const float* W_de = (const float*)d_in[11];
  const float* b_de = (const float*)d_in[12];
  float* out = (float*)d_out;
  float* ws  = (float*)d_ws;

  float* u    = ws;                                   // 1024*2048
  float* ctab = u + (size_t)T_ROWS * EDIM;            // 2048
  float* stab = ctab + EDIM;                          // 2048
  float* Wmr  = stab + EDIM;                          // 4*16*32
  float* Wmi  = Wmr + NLAYERS * NMODES * 32;          // 4*16*32
  float* b0r  = Wmi + NLAYERS * NMODES * 32;          // 4*32
  float* pw1  = b0r + NLAYERS * 32;                   // 4*32
  float* pb1  = pw1 + NLAYERS * 32;                   // 4*32
  unsigned short* basFh  = (unsigned short*)(pb1 + NLAYERS * 32);   // 128*64*8
  unsigned short* basFl  = basFh + 128 * 64 * 8;                    // 128*64*8
  unsigned short* coefFh = basFl + 128 * 64 * 8;                    // 1024*2*64*8
  unsigned short* coefFl = coefFh + (size_t)T_ROWS * 2 * 64 * 8;
  unsigned short* x_bf   = coefFl + (size_t)T_ROWS * 2 * 64 * 8;    // 1024*1024
  unsigned short* u_bf   = x_bf + (size_t)T_ROWS * IN_DIM;          // 1024*2048
  unsigned short* WenT   = u_bf + (size_t)T_ROWS * EDIM;            // [2048][1024]
  unsigned short* WdeT   = WenT + (size_t)EDIM * IN_DIM;            // [1024][2048]

  setup_all<<<4873, 256, 0, stream>>>(ctab, stab, basFh, basFl, fc0w, fc0b,
                                      swr, swi, pww, pwb, Wmr, Wmi, b0r, pw1, pb1,
                                      W_en, WenT, W_de, WdeT, x, x_bf);

  { dim3 g(EDIM / 64, T_ROWS / 64);
    gemm_mfma<<<g, 256, 0, stream>>>(x_bf, WenT, b_en, u, T_ROWS, EDIM, IN_DIM); }

  for (int l = 0; l < NLAYERS; ++l) {
    dft_coef<<<T_ROWS, 256, 0, stream>>>(u, ctab, stab,
        Wmr + l * NMODES * 32, Wmi + l * NMODES * 32, b0r + l * 32, pb1 + l * 32,
        coefFh, coefFl);
    if (l < NLAYERS - 1)
      recon_mfma<0><<<4 * T_ROWS, 256, 0, stream>>>(u, u_bf, basFh, basFl,
          coefFh, coefFl, pw1 + l * 32, f1w + l * 32, f1b + l);
    else
      recon_mfma<1><<<4 * T_ROWS, 256, 0, stream>>>(u, u_bf, basFh, basFl,
          coefFh, coefFl, pw1 + l * 32, f1w + l * 32, f1b + l);
  }

  { dim3 g(OUT_DIM / 64, T_ROWS / 64);
    gemm_mfma<<<g, 256, 0, stream>>>(u_bf, WdeT, b_de, out, T_ROWS, OUT_DIM, EDIM); }
}